// Round 7
// baseline (637.075 us; speedup 1.0000x reference)
//
#include <hip/hip_runtime.h>
#include <hip/hip_cooperative_groups.h>
#include <math.h>

namespace cg = cooperative_groups;

#define N_ROWS 65536
#define M_DIM  512
#define H_DIM  1024
#define EPS    1e-8f
#define NBLK   1024          // cooperative grid: 1024 blocks x 256 thr = 4 blocks/CU
#define ROWS_PER_BLK 64

// ---- workspace layout (floats) ----
#define WS_KVEC  0            // 512
#define WS_ERASE 512          // 512
#define WS_ADD   1024         // 512
#define WS_SCAL  1536         // [0]=beta_raw
#define WS_PSUM  2048         // 1024
#define WS_PART  4096         // 1024*512
#define WS_OUT1  528384       // 64*512

typedef float f32x4 __attribute__((ext_vector_type(4)));

__device__ __forceinline__ float sigmoidf_(float v) { return 1.f / (1.f + expf(-v)); }

struct P {
    const float *x, *h0, *c0, *mem, *rv;
    const float *W_ih, *b_ih, *W_hh, *b_hh;
    const float *W_fc, *b_fc, *W_key, *b_key, *W_beta, *b_beta;
    const float *W_erase, *b_erase, *W_add, *b_add;
    float *out, *h_out, *c_out, *mem_out, *read_out;
    float *kvec, *erase, *addv, *scal, *psum, *partial, *out1;
};

__global__ void __launch_bounds__(256, 4) k_fused(P p) {
    __shared__ float gval[4];
    __shared__ float red[256];
    __shared__ float skn[512];
    __shared__ float wsum[4];
    __shared__ float p_l[ROWS_PER_BLK];
    __shared__ float4 s_e[128];
    __shared__ float4 s_a[128];
    __shared__ float4 s_red[128];

    cg::grid_group grid = cg::this_grid();
    int bid = blockIdx.x;
    int t = threadIdx.x;
    int wid = t >> 6;
    int lane = t & 63;

    // ================= S0: gates matvec + LSTM cell (all 1024 blocks, j = bid) ======
    {
        int j = bid;
        int r = wid * H_DIM + j;
        const float4* Wi = (const float4*)(p.W_ih + (size_t)r * 1024);
        const float4* Wh = (const float4*)(p.W_hh + (size_t)r * 1024);
        const float4* xv = (const float4*)p.x;
        const float4* rvv = (const float4*)p.rv;
        const float4* hv = (const float4*)p.h0;
        float s = 0.f;
#pragma unroll
        for (int k = 0; k < 4; ++k) {
            int idx = k * 64 + lane;
            float4 wiv = Wi[idx];
            float4 in4 = (k < 2) ? xv[idx] : rvv[idx - 128];
            s += wiv.x * in4.x + wiv.y * in4.y + wiv.z * in4.z + wiv.w * in4.w;
            float4 whv = Wh[idx];
            float4 h4 = hv[idx];
            s += whv.x * h4.x + whv.y * h4.y + whv.z * h4.z + whv.w * h4.w;
        }
#pragma unroll
        for (int o = 32; o > 0; o >>= 1) s += __shfl_xor(s, o);
        if (lane == 0) gval[wid] = s + p.b_ih[r] + p.b_hh[r];
        __syncthreads();
        if (t == 0) {
            float ig = sigmoidf_(gval[0]);
            float fg = sigmoidf_(gval[1]);
            float gg = tanhf(gval[2]);
            float og = sigmoidf_(gval[3]);
            float c = fg * p.c0[j] + ig * gg;
            float h = og * tanhf(c);
            p.c_out[j] = c;
            p.h_out[j] = h;
        }
    }
    grid.sync();

    // ================= S1: 5 head matvecs (blocks 0..512) ===========================
    if (bid <= 512) {
        int wave = bid * 4 + wid;
        if (wave < 2049) {
            const float* Wrow;
            float bias;
            int kind, r;
            if (wave < 512)        { kind = 0; r = wave;        Wrow = p.W_fc    + (size_t)r * 1024; bias = p.b_fc[r]; }
            else if (wave < 1024)  { kind = 1; r = wave - 512;  Wrow = p.W_key   + (size_t)r * 1024; bias = p.b_key[r]; }
            else if (wave == 1024) { kind = 2; r = 0;           Wrow = p.W_beta;                     bias = p.b_beta[0]; }
            else if (wave < 1537)  { kind = 3; r = wave - 1025; Wrow = p.W_erase + (size_t)r * 1024; bias = p.b_erase[r]; }
            else                   { kind = 4; r = wave - 1537; Wrow = p.W_add   + (size_t)r * 1024; bias = p.b_add[r]; }
            const float4* Wv = (const float4*)Wrow;
            const float4* hv = (const float4*)p.h_out;
            float s = 0.f;
#pragma unroll
            for (int k = 0; k < 4; ++k) {
                int idx = k * 64 + lane;
                float4 w4 = Wv[idx];
                float4 h4 = hv[idx];
                s += w4.x * h4.x + w4.y * h4.y + w4.z * h4.z + w4.w * h4.w;
            }
#pragma unroll
            for (int o = 32; o > 0; o >>= 1) s += __shfl_xor(s, o);
            if (lane == 0) {
                float v = s + bias;
                if (kind == 0)      p.out[r]   = sigmoidf_(v);
                else if (kind == 1) p.kvec[r]  = tanhf(v);
                else if (kind == 2) p.scal[0]  = v;
                else if (kind == 3) p.erase[r] = sigmoidf_(v);
                else                p.addv[r]  = tanhf(v);
            }
        }
    }
    grid.sync();

    // ================= S2: sim+exp over this block's 64 rows; p -> LDS ==============
    float beta;
    {
        float v0 = p.kvec[t];
        float v1 = p.kvec[t + 256];
        red[t] = v0 * v0 + v1 * v1;
        __syncthreads();
#pragma unroll
        for (int s2 = 128; s2 > 0; s2 >>= 1) {
            if (t < s2) red[t] += red[t + s2];
            __syncthreads();
        }
        float invn = 1.f / (sqrtf(red[0]) + EPS);
        float braw = p.scal[0];
        beta = ((braw > 20.f) ? braw : log1pf(expf(braw))) + EPS;
        skn[t] = v0 * invn;
        skn[t + 256] = v1 * invn;
        __syncthreads();
        float4 k0 = ((const float4*)skn)[lane];
        float4 k1 = ((const float4*)skn)[64 + lane];
        size_t base = (size_t)bid * ROWS_PER_BLK + (size_t)wid * 16;
        float lsum = 0.f;
#pragma unroll 2
        for (int i = 0; i < 16; ++i) {
            size_t row = base + i;
            const float4* mv = (const float4*)(p.mem + row * M_DIM);
            float4 m0 = mv[lane];
            float4 m1 = mv[64 + lane];
            float dot = m0.x * k0.x + m0.y * k0.y + m0.z * k0.z + m0.w * k0.w
                      + m1.x * k1.x + m1.y * k1.y + m1.z * k1.z + m1.w * k1.w;
            float ss  = m0.x * m0.x + m0.y * m0.y + m0.z * m0.z + m0.w * m0.w
                      + m1.x * m1.x + m1.y * m1.y + m1.z * m1.z + m1.w * m1.w;
#pragma unroll
            for (int o = 32; o > 0; o >>= 1) {
                dot += __shfl_xor(dot, o);
                ss  += __shfl_xor(ss, o);
            }
            float pe = expf(beta * (dot / (sqrtf(ss) + EPS)));
            if (lane == 0) {
                p_l[wid * 16 + i] = pe;
                lsum += pe;
            }
        }
        if (lane == 0) wsum[wid] = lsum;
        __syncthreads();
        if (t == 0) p.psum[bid] = (wsum[0] + wsum[1]) + (wsum[2] + wsum[3]);
    }
    grid.sync();

    // ================= S3: memory update + read partial (all blocks) ================
    {
        float s = 0.f;
#pragma unroll
        for (int i = 0; i < 4; ++i) s += p.psum[t + i * 256];
        red[t] = s;
        __syncthreads();
#pragma unroll
        for (int s2 = 128; s2 > 0; s2 >>= 1) {
            if (t < s2) red[t] += red[t + s2];
            __syncthreads();
        }
        float winv = 1.f / red[0];
        if (t < 128) {
            s_e[t] = ((const float4*)p.erase)[t];
            s_a[t] = ((const float4*)p.addv)[t];
        }
        __syncthreads();
        int rowBase = bid * ROWS_PER_BLK;
        int sub = t >> 7;
        int c4  = t & 127;
        float4 e4 = s_e[c4];
        float4 a4 = s_a[c4];
        float4 acc = make_float4(0.f, 0.f, 0.f, 0.f);
#pragma unroll 4
        for (int it = 0; it < 32; ++it) {
            int row = rowBase + it * 2 + sub;
            float wr = p_l[it * 2 + sub] * winv;
            float4 m4 = ((const float4*)(p.mem + (size_t)row * M_DIM))[c4];
            f32x4 n4;
            n4.x = m4.x * (1.f - wr * e4.x) + wr * a4.x;
            n4.y = m4.y * (1.f - wr * e4.y) + wr * a4.y;
            n4.z = m4.z * (1.f - wr * e4.z) + wr * a4.z;
            n4.w = m4.w * (1.f - wr * e4.w) + wr * a4.w;
            __builtin_nontemporal_store(n4, (f32x4*)(p.mem_out + (size_t)row * M_DIM) + c4);
            acc.x += wr * n4.x;
            acc.y += wr * n4.y;
            acc.z += wr * n4.z;
            acc.w += wr * n4.w;
        }
        if (sub) s_red[c4] = acc;
        __syncthreads();
        if (!sub) {
            float4 o = s_red[c4];
            acc.x += o.x; acc.y += o.y; acc.z += o.z; acc.w += o.w;
            ((float4*)(p.partial + (size_t)bid * M_DIM))[c4] = acc;
        }
    }
    grid.sync();

    // ================= S4: read reduction stage 1 (blocks 0..63) ====================
    if (bid < 64) {
        float s0 = 0.f, s1 = 0.f;
        int b0 = bid * 16;
#pragma unroll 4
        for (int b = b0; b < b0 + 16; ++b) {
            s0 += p.partial[(size_t)b * M_DIM + t];
            s1 += p.partial[(size_t)b * M_DIM + 256 + t];
        }
        p.out1[(size_t)bid * M_DIM + t] = s0;
        p.out1[(size_t)bid * M_DIM + 256 + t] = s1;
    }
    grid.sync();

    // ================= S5: read reduction stage 2 (block 0) =========================
    if (bid == 0) {
        float s0 = 0.f, s1 = 0.f;
#pragma unroll 4
        for (int g = 0; g < 64; ++g) {
            s0 += p.out1[(size_t)g * M_DIM + t];
            s1 += p.out1[(size_t)g * M_DIM + 256 + t];
        }
        p.read_out[t] = s0;
        p.read_out[t + 256] = s1;
    }
}

extern "C" void kernel_launch(void* const* d_in, const int* in_sizes, int n_in,
                              void* d_out, int out_size, void* d_ws, size_t ws_size,
                              hipStream_t stream) {
    P prm;
    prm.x      = (const float*)d_in[0];
    prm.h0     = (const float*)d_in[1];
    prm.c0     = (const float*)d_in[2];
    prm.mem    = (const float*)d_in[3];
    prm.rv     = (const float*)d_in[4];
    prm.W_ih   = (const float*)d_in[5];
    prm.b_ih   = (const float*)d_in[6];
    prm.W_hh   = (const float*)d_in[7];
    prm.b_hh   = (const float*)d_in[8];
    prm.W_fc   = (const float*)d_in[9];
    prm.b_fc   = (const float*)d_in[10];
    prm.W_key  = (const float*)d_in[11];
    prm.b_key  = (const float*)d_in[12];
    prm.W_beta = (const float*)d_in[13];
    prm.b_beta = (const float*)d_in[14];
    prm.W_erase= (const float*)d_in[15];
    prm.b_erase= (const float*)d_in[16];
    prm.W_add  = (const float*)d_in[17];
    prm.b_add  = (const float*)d_in[18];

    float* out = (float*)d_out;
    prm.out      = out;                                    // 512
    prm.h_out    = out + 512;                              // 1024
    prm.c_out    = out + 1536;                             // 1024
    prm.mem_out  = out + 2560;                             // N*M
    prm.read_out = prm.mem_out + (size_t)N_ROWS * M_DIM;   // 512

    float* ws = (float*)d_ws;
    prm.kvec    = ws + WS_KVEC;
    prm.erase   = ws + WS_ERASE;
    prm.addv    = ws + WS_ADD;
    prm.scal    = ws + WS_SCAL;
    prm.psum    = ws + WS_PSUM;
    prm.partial = ws + WS_PART;
    prm.out1    = ws + WS_OUT1;

    void* args[] = { &prm };
    (void)hipLaunchCooperativeKernel((const void*)k_fused, dim3(NBLK), dim3(256),
                                     args, 0, stream);
}

// Round 8
// 91.171 us; speedup vs baseline: 6.9877x; 6.9877x over previous
//
#include <hip/hip_runtime.h>
#include <math.h>

#define N_ROWS 65536
#define M_DIM  512
#define H_DIM  1024
#define EPS    1e-8f
#define NBLK_U 2048   // k_update blocks (32 rows each)
#define NBLK_S 2048   // k_simexp blocks (32 rows each)

typedef float f32x4 __attribute__((ext_vector_type(4)));

__device__ __forceinline__ float sigmoidf_(float v) { return 1.f / (1.f + expf(-v)); }

// ---- workspace layout (floats) ----
#define WS_KVEC  0          // 512
#define WS_ERASE 512        // 512
#define WS_ADD   1024       // 512
#define WS_SCAL  1536       // [0]=beta_raw
#define WS_P     2048       // 65536 unnormalized exp(beta*sim)
#define WS_PSUM  67584      // 2048 per-simexp-block sums
#define WS_PART  69632      // 2048*512 per-update-block read partials
#define WS_OUT1  1118208    // 64*512 stage-1 reduced partials

// ---- fused gates matvec + LSTM cell: 1024 blocks x 256 (4 waves = gates i,f,g,o of one j) ----
__global__ void __launch_bounds__(256) k_gatecell(
        const float* __restrict__ x, const float* __restrict__ rv,
        const float* __restrict__ h0, const float* __restrict__ c0,
        const float* __restrict__ W_ih, const float* __restrict__ b_ih,
        const float* __restrict__ W_hh, const float* __restrict__ b_hh,
        float* __restrict__ h_out, float* __restrict__ c_out) {
    __shared__ float gval[4];
    int j = blockIdx.x;                 // hidden index 0..1023
    int wid = threadIdx.x >> 6;         // gate kind 0..3 (i,f,g,o)
    int lane = threadIdx.x & 63;
    int r = wid * H_DIM + j;            // gate row in [0,4096)
    const float4* Wi = (const float4*)(W_ih + (size_t)r * 1024);
    const float4* Wh = (const float4*)(W_hh + (size_t)r * 1024);
    const float4* xv = (const float4*)x;
    const float4* rvv = (const float4*)rv;
    const float4* hv = (const float4*)h0;
    float s = 0.f;
#pragma unroll
    for (int k = 0; k < 4; ++k) {
        int idx = k * 64 + lane;            // 0..255 float4s
        float4 wiv = Wi[idx];
        float4 in4 = (k < 2) ? xv[idx] : rvv[idx - 128];
        s += wiv.x * in4.x + wiv.y * in4.y + wiv.z * in4.z + wiv.w * in4.w;
        float4 whv = Wh[idx];
        float4 h4 = hv[idx];
        s += whv.x * h4.x + whv.y * h4.y + whv.z * h4.z + whv.w * h4.w;
    }
#pragma unroll
    for (int o = 32; o > 0; o >>= 1) s += __shfl_xor(s, o);
    if (lane == 0) gval[wid] = s + b_ih[r] + b_hh[r];
    __syncthreads();
    if (threadIdx.x == 0) {
        float ig = sigmoidf_(gval[0]);
        float fg = sigmoidf_(gval[1]);
        float gg = tanhf(gval[2]);
        float og = sigmoidf_(gval[3]);
        float c = fg * c0[j] + ig * gg;
        float h = og * tanhf(c);
        c_out[j] = c;
        h_out[j] = h;
    }
}

// ---- 5 head matvecs vs h; one wave per output row (2049 rows) ----
__global__ void __launch_bounds__(256) k_heads(
        const float* __restrict__ h,
        const float* __restrict__ W_fc, const float* __restrict__ b_fc,
        const float* __restrict__ W_key, const float* __restrict__ b_key,
        const float* __restrict__ W_beta, const float* __restrict__ b_beta,
        const float* __restrict__ W_erase, const float* __restrict__ b_erase,
        const float* __restrict__ W_add, const float* __restrict__ b_add,
        float* __restrict__ out, float* __restrict__ kvec,
        float* __restrict__ scal, float* __restrict__ erase,
        float* __restrict__ addv) {
    int wave = (blockIdx.x * blockDim.x + threadIdx.x) >> 6;
    int lane = threadIdx.x & 63;
    if (wave >= 2049) return;
    const float* Wrow;
    float bias;
    int kind, r;
    if (wave < 512)        { kind = 0; r = wave;        Wrow = W_fc    + (size_t)r * 1024; bias = b_fc[r]; }
    else if (wave < 1024)  { kind = 1; r = wave - 512;  Wrow = W_key   + (size_t)r * 1024; bias = b_key[r]; }
    else if (wave == 1024) { kind = 2; r = 0;           Wrow = W_beta;                     bias = b_beta[0]; }
    else if (wave < 1537)  { kind = 3; r = wave - 1025; Wrow = W_erase + (size_t)r * 1024; bias = b_erase[r]; }
    else                   { kind = 4; r = wave - 1537; Wrow = W_add   + (size_t)r * 1024; bias = b_add[r]; }
    const float4* Wv = (const float4*)Wrow;
    const float4* hv = (const float4*)h;
    float s = 0.f;
#pragma unroll
    for (int k = 0; k < 4; ++k) {
        int idx = k * 64 + lane;
        float4 w4 = Wv[idx];
        float4 h4 = hv[idx];
        s += w4.x * h4.x + w4.y * h4.y + w4.z * h4.z + w4.w * h4.w;
    }
#pragma unroll
    for (int o = 32; o > 0; o >>= 1) s += __shfl_xor(s, o);
    if (lane == 0) {
        float v = s + bias;
        if (kind == 0)      out[r]   = sigmoidf_(v);
        else if (kind == 1) kvec[r]  = tanhf(v);
        else if (kind == 2) scal[0]  = v;               // raw beta
        else if (kind == 3) erase[r] = sigmoidf_(v);
        else                addv[r]  = tanhf(v);
    }
}

// ---- sim + exp fused: p[n] = exp(beta * cos(mem[n], k)); per-block partial sums ----
// each block redundantly computes ||kvec|| and beta (deterministic, L2-hit)
__global__ void __launch_bounds__(256) k_simexp(
        const float* __restrict__ mem, const float* __restrict__ kvec,
        const float* __restrict__ scal,
        float* __restrict__ p, float* __restrict__ psum) {
    __shared__ float red[256];
    __shared__ float skn[512];
    __shared__ float wsum[4];
    int t = threadIdx.x;
    float v0 = kvec[t];
    float v1 = kvec[t + 256];
    red[t] = v0 * v0 + v1 * v1;
    __syncthreads();
#pragma unroll
    for (int s2 = 128; s2 > 0; s2 >>= 1) {
        if (t < s2) red[t] += red[t + s2];
        __syncthreads();
    }
    float invn = 1.f / (sqrtf(red[0]) + EPS);
    float braw = scal[0];
    float beta = ((braw > 20.f) ? braw : log1pf(expf(braw))) + EPS;
    skn[t] = v0 * invn;
    skn[t + 256] = v1 * invn;
    __syncthreads();
    int wid = t >> 6, lane = t & 63;
    float4 k0 = ((const float4*)skn)[lane];
    float4 k1 = ((const float4*)skn)[64 + lane];
    int gw = blockIdx.x * 4 + wid;          // 0..8191
    size_t base = (size_t)gw * 8;           // 8 consecutive rows per wave
    float lsum = 0.f;
#pragma unroll 2
    for (int i = 0; i < 8; ++i) {
        size_t row = base + i;
        const float4* mv = (const float4*)(mem + row * M_DIM);
        float4 m0 = mv[lane];
        float4 m1 = mv[64 + lane];
        float dot = m0.x * k0.x + m0.y * k0.y + m0.z * k0.z + m0.w * k0.w
                  + m1.x * k1.x + m1.y * k1.y + m1.z * k1.z + m1.w * k1.w;
        float ss  = m0.x * m0.x + m0.y * m0.y + m0.z * m0.z + m0.w * m0.w
                  + m1.x * m1.x + m1.y * m1.y + m1.z * m1.z + m1.w * m1.w;
#pragma unroll
        for (int o = 32; o > 0; o >>= 1) {
            dot += __shfl_xor(dot, o);
            ss  += __shfl_xor(ss, o);
        }
        float pe = expf(beta * (dot / (sqrtf(ss) + EPS)));
        if (lane == 0) {
            p[row] = pe;
            lsum += pe;
        }
    }
    if (lane == 0) wsum[wid] = lsum;
    __syncthreads();
    if (t == 0) psum[blockIdx.x] = (wsum[0] + wsum[1]) + (wsum[2] + wsum[3]);
}

// ---- mem_new + partial read_new; 2048 blocks x 256, 32 rows/block ----
// each block redundantly reduces psum[0..2047] -> S (deterministic)
// mem_out stores are NON-TEMPORAL: stream past L3 so `memory` stays resident
__global__ void __launch_bounds__(256) k_update(
        const float* __restrict__ mem, const float* __restrict__ p,
        const float* __restrict__ psum,
        const float* __restrict__ erase, const float* __restrict__ addv,
        float* __restrict__ mem_out, float* __restrict__ partial) {
    __shared__ float red[256];
    __shared__ float4 s_e[128];
    __shared__ float4 s_a[128];
    __shared__ float  s_w[32];
    __shared__ float4 s_red[128];
    int t = threadIdx.x;
    float s = 0.f;
#pragma unroll
    for (int i = 0; i < 8; ++i) s += psum[t + i * 256];
    red[t] = s;
    __syncthreads();
#pragma unroll
    for (int s2 = 128; s2 > 0; s2 >>= 1) {
        if (t < s2) red[t] += red[t + s2];
        __syncthreads();
    }
    float winv = 1.f / red[0];
    if (t < 128) {
        s_e[t] = ((const float4*)erase)[t];
        s_a[t] = ((const float4*)addv)[t];
    }
    int rowBase = blockIdx.x * 32;
    if (t < 32) s_w[t] = p[rowBase + t] * winv;
    __syncthreads();
    int sub = t >> 7;     // 0/1: which of the 2 rows per iteration
    int c4  = t & 127;    // float4 column index
    float4 e4 = s_e[c4];
    float4 a4 = s_a[c4];
    float4 acc = make_float4(0.f, 0.f, 0.f, 0.f);
#pragma unroll 4
    for (int it = 0; it < 16; ++it) {
        int row = rowBase + it * 2 + sub;
        float wr = s_w[it * 2 + sub];
        float4 m4 = ((const float4*)(mem + (size_t)row * M_DIM))[c4];
        f32x4 n4;
        n4.x = m4.x * (1.f - wr * e4.x) + wr * a4.x;
        n4.y = m4.y * (1.f - wr * e4.y) + wr * a4.y;
        n4.z = m4.z * (1.f - wr * e4.z) + wr * a4.z;
        n4.w = m4.w * (1.f - wr * e4.w) + wr * a4.w;
        __builtin_nontemporal_store(n4, (f32x4*)(mem_out + (size_t)row * M_DIM) + c4);
        acc.x += wr * n4.x;
        acc.y += wr * n4.y;
        acc.z += wr * n4.z;
        acc.w += wr * n4.w;
    }
    if (sub) s_red[c4] = acc;
    __syncthreads();
    if (!sub) {
        float4 o = s_red[c4];
        acc.x += o.x; acc.y += o.y; acc.z += o.z; acc.w += o.w;
        ((float4*)(partial + (size_t)blockIdx.x * M_DIM))[c4] = acc;
    }
}

// ---- stage-1 read reduction: 64 blocks x 256; block g sums b in [g*32, g*32+32) ----
__global__ void __launch_bounds__(256) k_red1(const float* __restrict__ partial,
                                              float* __restrict__ out1) {
    int g = blockIdx.x, t = threadIdx.x;
    float s0 = 0.f, s1 = 0.f;
    int b0 = g * 32;
#pragma unroll 4
    for (int b = b0; b < b0 + 32; ++b) {
        s0 += partial[(size_t)b * M_DIM + t];
        s1 += partial[(size_t)b * M_DIM + 256 + t];
    }
    out1[(size_t)g * M_DIM + t] = s0;
    out1[(size_t)g * M_DIM + 256 + t] = s1;
}

// ---- stage-2: 1 block x 512 ----
__global__ void __launch_bounds__(512) k_red2(const float* __restrict__ out1,
                                              float* __restrict__ read_new) {
    int t = threadIdx.x;
    float s = 0.f;
#pragma unroll 4
    for (int g = 0; g < 64; ++g) s += out1[(size_t)g * M_DIM + t];
    read_new[t] = s;
}

extern "C" void kernel_launch(void* const* d_in, const int* in_sizes, int n_in,
                              void* d_out, int out_size, void* d_ws, size_t ws_size,
                              hipStream_t stream) {
    const float* x        = (const float*)d_in[0];
    const float* h0       = (const float*)d_in[1];
    const float* c0       = (const float*)d_in[2];
    const float* memory   = (const float*)d_in[3];
    const float* read_vec = (const float*)d_in[4];
    const float* W_ih     = (const float*)d_in[5];
    const float* b_ih     = (const float*)d_in[6];
    const float* W_hh     = (const float*)d_in[7];
    const float* b_hh     = (const float*)d_in[8];
    const float* W_fc     = (const float*)d_in[9];
    const float* b_fc     = (const float*)d_in[10];
    const float* W_key    = (const float*)d_in[11];
    const float* b_key    = (const float*)d_in[12];
    const float* W_beta   = (const float*)d_in[13];
    const float* b_beta   = (const float*)d_in[14];
    const float* W_erase  = (const float*)d_in[15];
    const float* b_erase  = (const float*)d_in[16];
    const float* W_add    = (const float*)d_in[17];
    const float* b_add    = (const float*)d_in[18];

    float* out      = (float*)d_out;                       // 512
    float* h_out    = out + 512;                           // 1024
    float* c_out    = h_out + 1024;                        // 1024
    float* mem_out  = c_out + 1024;                        // N*M
    float* read_out = mem_out + (size_t)N_ROWS * M_DIM;    // 512

    float* ws     = (float*)d_ws;
    float* kvec   = ws + WS_KVEC;
    float* erase  = ws + WS_ERASE;
    float* addv   = ws + WS_ADD;
    float* scal   = ws + WS_SCAL;
    float* p      = ws + WS_P;
    float* psum   = ws + WS_PSUM;
    float* part   = ws + WS_PART;
    float* out1   = ws + WS_OUT1;

    k_gatecell<<<1024, 256, 0, stream>>>(x, read_vec, h0, c0, W_ih, b_ih, W_hh, b_hh,
                                         h_out, c_out);
    k_heads<<<513, 256, 0, stream>>>(h_out, W_fc, b_fc, W_key, b_key, W_beta, b_beta,
                                     W_erase, b_erase, W_add, b_add,
                                     out, kvec, scal, erase, addv);
    k_simexp<<<NBLK_S, 256, 0, stream>>>(memory, kvec, scal, p, psum);
    k_update<<<NBLK_U, 256, 0, stream>>>(memory, p, psum, erase, addv, mem_out, part);
    k_red1<<<64, 256, 0, stream>>>(part, out1);
    k_red2<<<1, 512, 0, stream>>>(out1, read_out);
}